// Round 10
// baseline (143.590 us; speedup 1.0000x reference)
//
#include <hip/hip_runtime.h>
#include <math.h>

#define THREADS 256
#define CAP 512
#define HIST_BINS 4096
#define RAW_THRESH 2.5f
#define SEGLEN 8192   // floats per sweep segment (32 KB)
#define SEGCAP 192    // per-segment collection cap (mean ~51, sigma ~7)

typedef float f32x4 __attribute__((ext_vector_type(4)));

__device__ __forceinline__ unsigned orderKey(float f) {
    unsigned u = __float_as_uint(f);
    return (u & 0x80000000u) ? ~u : (u | 0x80000000u);
}

#define MAX4(vv) fmaxf(fmaxf((vv).x, (vv).y), fmaxf((vv).z, (vv).w))

// ws layout, derived identically in every kernel from device-readable nrows.
struct WS {
    int* mark;     // nrows
    int* cnt;      // nrows
    int* meta;     // 8  (meta[0] = nneeded)
    int* rowlist;  // nrows (needed rows, ascending)
    int2* gpair;   // nrows*CAP packed (float bits, idx)
    float* prob;   // total
    int* tok;      // total
};
__device__ __forceinline__ WS ws_layout(void* ws, int nrows, int total) {
    WS w;
    w.mark = (int*)ws;
    w.cnt  = w.mark + nrows;
    w.meta = w.cnt + nrows;
    w.rowlist = w.meta + 8;
    size_t off = (size_t)(3 * nrows + 16);
    off = (off + 1) & ~(size_t)1;          // 8-byte align for int2
    w.gpair = (int2*)((int*)ws + off);
    w.prob  = (float*)(w.gpair + (size_t)nrows * CAP);
    w.tok   = (int*)(w.prob + total);
    return w;
}

__global__ void zero_kernel(const int* __restrict__ cuq, int bsz, int total, void* ws) {
    const int nrows = cuq[bsz];
    WS w = ws_layout(ws, nrows, total);
    for (int i = blockIdx.x * blockDim.x + threadIdx.x; i < nrows; i += gridDim.x * blockDim.x) {
        w.mark[i] = 0;
        w.cnt[i] = 0;
    }
    if (blockIdx.x == 0 && threadIdx.x < 8) w.meta[threadIdx.x] = 0;
}

// One thread per candidate: mark referenced rows.
__global__ void mark_kernel(const int* __restrict__ rel_idx,
                            const int* __restrict__ cuf,
                            const int* __restrict__ cuq,
                            int bsz, int total, void* ws) {
    const int t = blockIdx.x * blockDim.x + threadIdx.x;
    if (t >= total) return;
    const int nrows = cuq[bsz];
    WS w = ws_layout(ws, nrows, total);
    int lo = 0, hi = bsz;
    while (hi - lo > 1) { int mid = (lo + hi) >> 1; if (t >= cuf[mid]) lo = mid; else hi = mid; }
    w.mark[cuq[lo] + rel_idx[t]] = 1;
}

// Single block: ordered compaction of marked rows into rowlist (prefix sum).
__global__ __launch_bounds__(256) void compact_kernel(
    const int* __restrict__ cuq, int bsz, int total, void* ws)
{
    __shared__ int sm[4096];
    __shared__ int part[256];
    __shared__ int s_off;
    const int tid = threadIdx.x;
    const int nrows = cuq[bsz];
    WS w = ws_layout(ws, nrows, total);

    if (tid == 0) s_off = 0;
    __syncthreads();
    for (int base = 0; base < nrows; base += 4096) {
        const int tile = (nrows - base < 4096) ? nrows - base : 4096;
        for (int j = tid; j < tile; j += 256) sm[j] = w.mark[base + j];
        __syncthreads();
        const int c0 = tid * 16;
        const int c1 = (c0 + 16 < tile) ? c0 + 16 : tile;
        int cnt = 0;
        for (int j = c0; j < c1; ++j) cnt += sm[j] ? 1 : 0;
        part[tid] = cnt;
        __syncthreads();
        if (tid == 0) {
            int acc = s_off;
            for (int q = 0; q < 256; ++q) { int v = part[q]; part[q] = acc; acc += v; }
            s_off = acc;
        }
        __syncthreads();
        int off = part[tid];
        for (int j = c0; j < c1; ++j)
            if (sm[j]) w.rowlist[off++] = base + j;
        __syncthreads();
    }
    if (tid == 0) w.meta[0] = s_off;
}

// Address-ordered sweep: consecutive blocks own consecutive 32KB segments of
// the NEEDED rows (compacted list). LDS-local collection, one atomic + packed
// int2 flush per segment.
__global__ __launch_bounds__(THREADS, 8) void sweep_kernel(
    const float* __restrict__ logits,
    const int* __restrict__ cuq,
    int bsz, int total, long long logits_n, void* ws)
{
    __shared__ float s_v[SEGCAP];
    __shared__ int   s_i[SEGCAP];
    __shared__ int s_ns, s_base;

    const int tid = threadIdx.x;
    const int nrows = cuq[bsz];
    const int vocab = (int)(logits_n / (long long)nrows);
    WS w = ws_layout(ws, nrows, total);

    const int spr = (vocab + SEGLEN - 1) / SEGLEN;
    const long long nseg = (long long)w.meta[0] * spr;

#define SC1(x, gi) \
    if ((x) >= RAW_THRESH) { int p = atomicAdd(&s_ns, 1); if (p < SEGCAP) { s_v[p] = (x); s_i[p] = (gi); } }
#define SC4(vv, base) \
    SC1((vv).x, (base)) SC1((vv).y, (base) + 1) SC1((vv).z, (base) + 2) SC1((vv).w, (base) + 3)

    for (long long s = blockIdx.x; s < nseg; s += gridDim.x) {
        const int r  = w.rowlist[s / spr];
        const int s0 = (int)(s % spr) * SEGLEN;
        const int s1 = (s0 + SEGLEN < vocab) ? s0 + SEGLEN : vocab;
        if (tid == 0) s_ns = 0;
        __syncthreads();

        const float* rp = logits + (long long)r * (long long)vocab;
        const f32x4* rp4 = (const f32x4*)rp;
        const int c0 = s0 >> 2, c1 = s1 >> 2;

        int i = c0 + tid;
        for (; i + 3 * THREADS < c1; i += 4 * THREADS) {
            f32x4 a = rp4[i];
            f32x4 b = rp4[i + THREADS];
            f32x4 c = rp4[i + 2 * THREADS];
            f32x4 d = rp4[i + 3 * THREADS];
            if (MAX4(a) >= RAW_THRESH) { SC4(a, i << 2) }
            if (MAX4(b) >= RAW_THRESH) { SC4(b, (i + THREADS) << 2) }
            if (MAX4(c) >= RAW_THRESH) { SC4(c, (i + 2 * THREADS) << 2) }
            if (MAX4(d) >= RAW_THRESH) { SC4(d, (i + 3 * THREADS) << 2) }
        }
        for (; i < c1; i += THREADS) {
            f32x4 a = rp4[i];
            if (MAX4(a) >= RAW_THRESH) { SC4(a, i << 2) }
        }
        for (int j = (c1 << 2) + tid; j < s1; j += THREADS) {
            float x = rp[j];
            SC1(x, j)
        }
        __syncthreads();

        const int ns = s_ns;
        if (ns > SEGCAP) {
            // overflow: poison so the token kernel takes the exact fallback
            if (tid == 0) atomicAdd(&w.cnt[r], CAP + 1);
        } else {
            if (tid == 0) s_base = atomicAdd(&w.cnt[r], ns);
            __syncthreads();
            const int base = s_base;
            for (int j = tid; j < ns; j += THREADS) {
                int p = base + j;
                if (p < CAP)
                    w.gpair[(size_t)r * CAP + p] = make_int2(__float_as_int(s_v[j]), s_i[j]);
            }
        }
        __syncthreads();
    }
#undef SC1
#undef SC4
}

// One wave per candidate token: load packed pairs, scale, rank-sort scaled
// (desc, idx-asc; order among equal values is output-irrelevant), exact
// epilogue. Full-row histogram fallback for under/overflowed rows.
__global__ __launch_bounds__(64) void token_kernel(
    const float* __restrict__ logits,
    const int* __restrict__ rel_idx,
    const int* __restrict__ cuf,
    const int* __restrict__ cuq,
    const float* __restrict__ temps,
    const int* __restrict__ topk_p,
    const float* __restrict__ topp_p,
    int bsz, int total, long long logits_n, void* ws)
{
    __shared__ union {
        struct { float sv[CAP]; int si[CAP]; float e[CAP]; } a;  // 6 KB
        int hist[HIST_BINS];                                     // 16 KB
    } u;
    __shared__ int s_m, s_amax, s_n;
    __shared__ unsigned s_T, s_maxkey;

    const int t = blockIdx.x;
    const int l = threadIdx.x;
    const int nrows = cuq[bsz];
    const int vocab = (int)(logits_n / (long long)nrows);
    int kk = topk_p[0];
    if (kk > vocab) kk = vocab;

    WS w = ws_layout(ws, nrows, total);

    int lo = 0, hi = bsz;
    while (hi - lo > 1) { int mid = (lo + hi) >> 1; if (t >= cuf[mid]) lo = mid; else hi = mid; }
    const int row = cuq[lo] + rel_idx[t];
    const float T = temps[t];
    const float* rp = logits + (long long)row * (long long)vocab;
    int n = w.cnt[row];

    if (n >= kk && n <= CAP) {
        for (int j = l; j < n; j += 64) {
            int2 pr = w.gpair[(size_t)row * CAP + j];
            u.a.sv[j] = __int_as_float(pr.x) / T;
            u.a.si[j] = pr.y;
        }
        __syncthreads();
    } else {
        // ---- fallback: exact raw-space histogram over the full row ----
        for (int j = l; j < HIST_BINS; j += 64) u.hist[j] = 0;
        if (l == 0) { s_n = 0; s_maxkey = 0; }
        __syncthreads();
        for (int j = l; j < vocab; j += 64) {
            unsigned k = orderKey(rp[j]);
            atomicAdd(&u.hist[k >> 20], 1);
            atomicMax(&s_maxkey, k);
        }
        __syncthreads();
        if (l == 0) {
            int B = (int)(s_maxkey >> 20);
            int cum = 0;
            while (true) {
                cum += u.hist[B];
                if (cum >= kk || B == 0) break;
                --B;
            }
            s_T = ((unsigned)B) << 20;
        }
        __syncthreads();
        const unsigned Tk = s_T;
        __syncthreads();   // hist reads done before union reuse
        for (int j = l; j < vocab; j += 64) {
            float a = rp[j];
            if (orderKey(a) >= Tk) {
                int p = atomicAdd(&s_n, 1);
                if (p < CAP) { u.a.sv[p] = a / T; u.a.si[p] = j; }
            }
        }
        __syncthreads();
        n = s_n;
        if (n > CAP) n = CAP;
        if (kk > n) kk = n;
    }

    // ---- rank-sort scaled (desc, idx-asc) in LDS ----
    {
        float vs[CAP / 64]; int ids[CAP / 64]; int rks[CAP / 64]; int c2 = 0;
        for (int j = l; j < n; j += 64) {
            float vv = u.a.sv[j]; int ii = u.a.si[j];
            int r2 = 0;
            for (int q = 0; q < n; ++q) {
                float x = u.a.sv[q];
                r2 += (x > vv) || (x == vv && u.a.si[q] < ii);
            }
            vs[c2] = vv; ids[c2] = ii; rks[c2] = r2; ++c2;
        }
        __syncthreads();
        for (int j2 = 0; j2 < c2; ++j2) { u.a.sv[rks[j2]] = vs[j2]; u.a.si[rks[j2]] = ids[j2]; }
        __syncthreads();
    }

    const float M = u.a.sv[0];
    const float thrk = u.a.sv[kk - 1];

    int mcnt = 0;
    int cand = 0x7fffffff;
    for (int j = l; j < n; j += 64) {
        mcnt += (u.a.sv[j] >= thrk) ? 1 : 0;
        if (u.a.sv[j] == M && u.a.si[j] < cand) cand = u.a.si[j];
    }
    for (int off = 32; off > 0; off >>= 1) {
        mcnt += __shfl_down(mcnt, off);
        int oc = __shfl_down(cand, off);
        if (oc < cand) cand = oc;
    }
    if (l == 0) { s_m = mcnt; s_amax = cand; }
    __syncthreads();
    const int m = s_m;
    for (int j = l; j < m; j += 64) u.a.e[j] = expf(u.a.sv[j] - M);
    __syncthreads();
    if (l == 0) {
        float Z1 = 0.f;
        for (int j = 0; j < m; ++j) Z1 += u.a.e[j];
        const float topp = topp_p[0];
        int jcut = m - 1;
        float c = 0.f;
        for (int j = 0; j < m; ++j) {
            float p = u.a.e[j] / Z1;
            c += p;
            if (c > topp) { jcut = j; break; }
        }
        float Z2 = 0.f;
        for (int j = 0; j <= jcut; ++j) Z2 += u.a.e[j];
        w.prob[t] = 1.0f / Z2;
        w.tok[t] = s_amax;
    }
}

// One wave per batch: stable sort by score desc, filter, write int32 outputs.
__global__ __launch_bounds__(64) void finalize_kernel(
    const int* __restrict__ rel_idx,
    const int* __restrict__ boff,
    const int* __restrict__ cuf,
    const int* __restrict__ cuq,
    const int* __restrict__ num_transfer,
    const float* __restrict__ thresholds,
    int bsz, int total, int L,
    void* ws,
    int* __restrict__ out)
{
    const int bq = blockIdx.x;
    const int l = threadIdx.x;
    const int nrows = cuq[bsz];
    WS w = ws_layout(ws, nrows, total);

    const int start = cuf[bq];
    int cnt = cuf[bq + 1] - start;
    if (cnt > L) cnt = L;

    __shared__ float ss[64]; __shared__ int stk[64]; __shared__ int sp[64];
    __shared__ float ss2[64]; __shared__ int stk2[64]; __shared__ int sp2[64];

    float score = -INFINITY; int tk = 0; int pos = 0;
    if (l < L) {
        if (l < cnt) {
            int t = start + l;
            score = w.prob[t];
            tk = w.tok[t];
            pos = rel_idx[t] + boff[bq];
        }
        ss[l] = score; stk[l] = tk; sp[l] = pos;
    }
    __syncthreads();
    if (l < L) {
        int r = 0;
        for (int j = 0; j < L; ++j) {
            float x = ss[j];
            r += (x > score) || (x == score && j < l);
        }
        ss2[r] = score; stk2[r] = tk; sp2[r] = pos;
    }
    __syncthreads();

    int k = num_transfer[bq]; if (k < 0) k = 0;
    const float thrb = thresholds[bq];
    bool kp = false;
    if (l < L) {
        float s = ss2[l];
        kp = (l < k) && (s >= thrb) && (s > -INFINITY);
        out[bq * L + l] = kp ? sp2[l] : 0;
        out[bsz * L + bq * L + l] = kp ? stk2[l] : -1;
    }
    unsigned long long mask = __ballot(kp);
    if (l == 0) out[2 * bsz * L + bq] = (int)__popcll(mask);
}

extern "C" void kernel_launch(void* const* d_in, const int* in_sizes, int n_in,
                              void* d_out, int out_size, void* d_ws, size_t ws_size,
                              hipStream_t stream) {
    const float* logits   = (const float*)d_in[0];
    const int*   rel      = (const int*)d_in[1];
    const int*   boff     = (const int*)d_in[2];
    const int*   cuf      = (const int*)d_in[3];
    const int*   cuq      = (const int*)d_in[4];
    const float* temps    = (const float*)d_in[5];
    const int*   ntr      = (const int*)d_in[6];
    const float* thr      = (const float*)d_in[7];
    const float* topp     = (const float*)d_in[8];
    const int*   topk     = (const int*)d_in[9];

    const int total = in_sizes[1];
    const int bsz   = in_sizes[6];
    const long long logits_n = (long long)in_sizes[0];
    const int L = (out_size - bsz) / (2 * bsz);   // block_size

    zero_kernel<<<64, 256, 0, stream>>>(cuq, bsz, total, d_ws);

    mark_kernel<<<(total + 255) / 256, 256, 0, stream>>>(
        rel, cuf, cuq, bsz, total, d_ws);

    compact_kernel<<<1, 256, 0, stream>>>(cuq, bsz, total, d_ws);

    sweep_kernel<<<2048, THREADS, 0, stream>>>(
        logits, cuq, bsz, total, logits_n, d_ws);

    token_kernel<<<total, 64, 0, stream>>>(
        logits, rel, cuf, cuq, temps, topk, topp, bsz, total, logits_n, d_ws);

    finalize_kernel<<<bsz, 64, 0, stream>>>(
        rel, boff, cuf, cuq, ntr, thr, bsz, total, L, d_ws, (int*)d_out);
}

// Round 11
// 109.108 us; speedup vs baseline: 1.3160x; 1.3160x over previous
//
#include <hip/hip_runtime.h>
#include <math.h>

#define THREADS 256
#define CAP 512
#define HIST_BINS 4096
#define RAW_THRESH 2.5f

typedef float f32x4 __attribute__((ext_vector_type(4)));

__device__ __forceinline__ unsigned orderKey(float f) {
    unsigned u = __float_as_uint(f);
    return (u & 0x80000000u) ? ~u : (u | 0x80000000u);
}

// ws layout, derived identically in every kernel from device-readable nrows.
struct WS {
    int* mark;     // nrows
    int* rowlist;  // nrows (distinct needed rows, unordered)
    int* meta;     // 8: [0]=nneeded, [1]=steal head
    float* svals; int* sidx; int* wsn;
    float* prob; int* tok;
};
__device__ __forceinline__ WS ws_layout(void* ws, int nrows, int total) {
    WS w;
    w.mark = (int*)ws;
    w.rowlist = w.mark + nrows;
    w.meta = w.rowlist + nrows;
    w.svals = (float*)(w.meta + 8);
    w.sidx  = (int*)(w.svals + (size_t)nrows * CAP);
    w.wsn   = w.sidx + (size_t)nrows * CAP;
    w.prob  = (float*)(w.wsn + nrows);
    w.tok   = (int*)(w.prob + total);
    return w;
}

__global__ void zero_kernel(const int* __restrict__ cuq, int bsz, int total, void* ws) {
    const int nrows = cuq[bsz];
    WS w = ws_layout(ws, nrows, total);
    for (int i = blockIdx.x * blockDim.x + threadIdx.x; i < nrows; i += gridDim.x * blockDim.x)
        w.mark[i] = 0;
    if (blockIdx.x == 0 && threadIdx.x < 8) w.meta[threadIdx.x] = 0;
}

// One thread per candidate: CAS-dedup referenced rows into rowlist.
__global__ void mark_kernel(const int* __restrict__ rel_idx,
                            const int* __restrict__ cuf,
                            const int* __restrict__ cuq,
                            int bsz, int total, void* ws) {
    const int t = blockIdx.x * blockDim.x + threadIdx.x;
    if (t >= total) return;
    const int nrows = cuq[bsz];
    WS w = ws_layout(ws, nrows, total);
    int lo = 0, hi = bsz;
    while (hi - lo > 1) { int mid = (lo + hi) >> 1; if (t >= cuf[mid]) lo = mid; else hi = mid; }
    const int row = cuq[lo] + rel_idx[t];
    if (atomicCAS(&w.mark[row], 0, 1) == 0) {
        int p = atomicAdd(&w.meta[0], 1);
        w.rowlist[p] = row;
    }
}

#define COLLECT1(x, gi) \
    if ((x) >= RAW_THRESH) { int p = atomicAdd(&s_n, 1); if (p < CAP) { u.a.v[p] = (x); u.a.id[p] = (gi); } }
#define COLLECT4(vv, base) \
    COLLECT1((vv).x, (base)) COLLECT1((vv).y, (base) + 1) \
    COLLECT1((vv).z, (base) + 2) COLLECT1((vv).w, (base) + 3)

// Work-stealing over distinct needed rows. Per row: r4's proven streaming
// core (plain f32x4 loads, 2x unroll, LDS collect at full 32-wave/CU
// occupancy), exact raw-space histogram fallback, LDS rank-sort, write
// sorted (val,idx)+count to ws.
__global__ __launch_bounds__(THREADS, 8) void row_kernel(
    const float* __restrict__ logits,
    const int* __restrict__ cuq,
    const int* __restrict__ topk_p,
    int bsz, int total, long long logits_n, void* ws)
{
    __shared__ union {
        struct { float v[CAP]; int id[CAP]; float sv[CAP]; int si[CAP]; } a;  // 8 KB
        int hist[HIST_BINS];                                                  // 16 KB
    } u;
    __shared__ int s_n, s_r;
    __shared__ unsigned s_T, s_maxkey;

    const int tid = threadIdx.x;
    const int nrows = cuq[bsz];
    const int vocab = (int)(logits_n / (long long)nrows);
    int kk = topk_p[0];
    if (kk > vocab) kk = vocab;

    WS w = ws_layout(ws, nrows, total);
    const int nneeded = w.meta[0];

    while (true) {
        if (tid == 0) {
            int i = atomicAdd(&w.meta[1], 1);
            s_r = (i < nneeded) ? w.rowlist[i] : -1;
            s_n = 0;
        }
        __syncthreads();
        const int r = s_r;
        if (r < 0) break;

        const float* rp = logits + (long long)r * (long long)vocab;
        const f32x4* rp4 = (const f32x4*)rp;
        const int nv4 = vocab >> 2;

        // ---- r4's streaming pass: 2 float4/thread/iter, plain loads ----
        int i = tid;
        for (; i + THREADS < nv4; i += 2 * THREADS) {
            f32x4 v0 = rp4[i];
            f32x4 v1 = rp4[i + THREADS];
            int b0 = i << 2, b1 = (i + THREADS) << 2;
            COLLECT1(v0.x, b0) COLLECT1(v0.y, b0 + 1) COLLECT1(v0.z, b0 + 2) COLLECT1(v0.w, b0 + 3)
            COLLECT1(v1.x, b1) COLLECT1(v1.y, b1 + 1) COLLECT1(v1.z, b1 + 2) COLLECT1(v1.w, b1 + 3)
        }
        for (; i < nv4; i += THREADS) {
            f32x4 v = rp4[i];
            COLLECT4(v, i << 2)
        }
        for (int j = (nv4 << 2) + tid; j < vocab; j += THREADS) {
            float x = rp[j];
            COLLECT1(x, j)
        }
        __syncthreads();
        int n = s_n;

        if (n < kk || n > CAP) {
            // ---- fallback: exact raw-space histogram threshold ----
            __syncthreads();
            for (int j = tid; j < HIST_BINS; j += THREADS) u.hist[j] = 0;
            if (tid == 0) { s_n = 0; s_maxkey = 0; }
            __syncthreads();
            for (int j = tid; j < vocab; j += THREADS) {
                unsigned k = orderKey(rp[j]);
                atomicAdd(&u.hist[k >> 20], 1);
                atomicMax(&s_maxkey, k);
            }
            __syncthreads();
            if (tid == 0) {
                int B = (int)(s_maxkey >> 20);
                int cum = 0;
                while (true) {
                    cum += u.hist[B];
                    if (cum >= kk || B == 0) break;
                    --B;
                }
                s_T = ((unsigned)B) << 20;
            }
            __syncthreads();
            const unsigned Tk = s_T;
            __syncthreads();
            for (int j = tid; j < vocab; j += THREADS) {
                float a = rp[j];
                if (orderKey(a) >= Tk) {
                    int p = atomicAdd(&s_n, 1);
                    if (p < CAP) { u.a.v[p] = a; u.a.id[p] = j; }
                }
            }
            __syncthreads();
            n = s_n;
            if (n > CAP) n = CAP;
        }

        // ---- rank-sort (value desc, original index asc) ----
        for (int j = tid; j < n; j += THREADS) {
            float v = u.a.v[j];
            int id = u.a.id[j];
            int rk = 0;
            for (int q = 0; q < n; ++q) {
                float x = u.a.v[q];
                rk += (x > v) || (x == v && u.a.id[q] < id);
            }
            u.a.sv[rk] = v;
            u.a.si[rk] = id;
        }
        __syncthreads();
        for (int j = tid; j < n; j += THREADS) {
            w.svals[(size_t)r * CAP + j] = u.a.sv[j];
            w.sidx[(size_t)r * CAP + j]  = u.a.si[j];
        }
        if (tid == 0) w.wsn[r] = n;
        __syncthreads();   // LDS + s_r reuse on next steal
    }
}

// One wave per candidate token: load the row's sorted raws (order preserved
// under /T), scale, top-k tie count, first-index argmax, exact sequential
// softmax / cumsum / top-p epilogue. Full-row histogram fallback kept.
__global__ __launch_bounds__(64) void token_kernel(
    const float* __restrict__ logits,
    const int* __restrict__ rel_idx,
    const int* __restrict__ cuf,
    const int* __restrict__ cuq,
    const float* __restrict__ temps,
    const int* __restrict__ topk_p,
    const float* __restrict__ topp_p,
    int bsz, int total, long long logits_n, void* ws)
{
    __shared__ union {
        struct { float sv[CAP]; int si[CAP]; float e[CAP]; } a;  // 6 KB
        int hist[HIST_BINS];                                     // 16 KB
    } u;
    __shared__ int s_m, s_amax, s_n;
    __shared__ unsigned s_T, s_maxkey;

    const int t = blockIdx.x;
    const int l = threadIdx.x;
    const int nrows = cuq[bsz];
    const int vocab = (int)(logits_n / (long long)nrows);
    int kk = topk_p[0];
    if (kk > vocab) kk = vocab;

    WS w = ws_layout(ws, nrows, total);

    int lo = 0, hi = bsz;
    while (hi - lo > 1) { int mid = (lo + hi) >> 1; if (t >= cuf[mid]) lo = mid; else hi = mid; }
    const int row = cuq[lo] + rel_idx[t];
    const float T = temps[t];
    const float* rp = logits + (long long)row * (long long)vocab;
    int n = w.wsn[row];

    if (n >= kk && n <= CAP) {
        // main path: already sorted by raw desc (idx-asc ties); /T preserves order
        for (int j = l; j < n; j += 64) {
            u.a.sv[j] = w.svals[(size_t)row * CAP + j] / T;
            u.a.si[j] = w.sidx[(size_t)row * CAP + j];
        }
        __syncthreads();
    } else {
        // ---- fallback: exact raw-space histogram over the full row ----
        for (int j = l; j < HIST_BINS; j += 64) u.hist[j] = 0;
        if (l == 0) { s_n = 0; s_maxkey = 0; }
        __syncthreads();
        for (int j = l; j < vocab; j += 64) {
            unsigned k = orderKey(rp[j]);
            atomicAdd(&u.hist[k >> 20], 1);
            atomicMax(&s_maxkey, k);
        }
        __syncthreads();
        if (l == 0) {
            int B = (int)(s_maxkey >> 20);
            int cum = 0;
            while (true) {
                cum += u.hist[B];
                if (cum >= kk || B == 0) break;
                --B;
            }
            s_T = ((unsigned)B) << 20;
        }
        __syncthreads();
        const unsigned Tk = s_T;
        __syncthreads();   // hist reads done before union reuse
        for (int j = l; j < vocab; j += 64) {
            float a = rp[j];
            if (orderKey(a) >= Tk) {
                int p = atomicAdd(&s_n, 1);
                if (p < CAP) { u.a.sv[p] = a / T; u.a.si[p] = j; }
            }
        }
        __syncthreads();
        n = s_n;
        if (n > CAP) n = CAP;
        if (kk > n) kk = n;
        // rank-sort (desc, idx-asc): gather per-lane, then rewrite
        float vs[CAP / 64]; int ids[CAP / 64]; int rks[CAP / 64]; int cnt2 = 0;
        for (int j = l; j < n; j += 64) {
            float vv = u.a.sv[j]; int ii = u.a.si[j];
            int r2 = 0;
            for (int q = 0; q < n; ++q) {
                float x = u.a.sv[q];
                r2 += (x > vv) || (x == vv && u.a.si[q] < ii);
            }
            vs[cnt2] = vv; ids[cnt2] = ii; rks[cnt2] = r2; ++cnt2;
        }
        __syncthreads();
        for (int j2 = 0; j2 < cnt2; ++j2) { u.a.sv[rks[j2]] = vs[j2]; u.a.si[rks[j2]] = ids[j2]; }
        __syncthreads();
    }

    const float M = u.a.sv[0];
    const float thrk = u.a.sv[kk - 1];

    int mcnt = 0;
    int cand = 0x7fffffff;
    for (int j = l; j < n; j += 64) {
        mcnt += (u.a.sv[j] >= thrk) ? 1 : 0;
        if (u.a.sv[j] == M && u.a.si[j] < cand) cand = u.a.si[j];
    }
    for (int off = 32; off > 0; off >>= 1) {
        mcnt += __shfl_down(mcnt, off);
        int oc = __shfl_down(cand, off);
        if (oc < cand) cand = oc;
    }
    if (l == 0) { s_m = mcnt; s_amax = cand; }
    __syncthreads();
    const int m = s_m;
    for (int j = l; j < m; j += 64) u.a.e[j] = expf(u.a.sv[j] - M);
    __syncthreads();
    if (l == 0) {
        float Z1 = 0.f;
        for (int j = 0; j < m; ++j) Z1 += u.a.e[j];
        const float topp = topp_p[0];
        int jcut = m - 1;
        float c = 0.f;
        for (int j = 0; j < m; ++j) {
            float p = u.a.e[j] / Z1;
            c += p;
            if (c > topp) { jcut = j; break; }
        }
        float Z2 = 0.f;
        for (int j = 0; j <= jcut; ++j) Z2 += u.a.e[j];
        w.prob[t] = 1.0f / Z2;
        w.tok[t] = s_amax;
    }
}

// One wave per batch: stable sort by score desc, filter, write int32 outputs.
__global__ __launch_bounds__(64) void finalize_kernel(
    const int* __restrict__ rel_idx,
    const int* __restrict__ boff,
    const int* __restrict__ cuf,
    const int* __restrict__ cuq,
    const int* __restrict__ num_transfer,
    const float* __restrict__ thresholds,
    int bsz, int total, int L,
    void* ws,
    int* __restrict__ out)
{
    const int bq = blockIdx.x;
    const int l = threadIdx.x;
    const int nrows = cuq[bsz];
    WS w = ws_layout(ws, nrows, total);

    const int start = cuf[bq];
    int cnt = cuf[bq + 1] - start;
    if (cnt > L) cnt = L;

    __shared__ float ss[64]; __shared__ int stk[64]; __shared__ int sp[64];
    __shared__ float ss2[64]; __shared__ int stk2[64]; __shared__ int sp2[64];

    float score = -INFINITY; int tk = 0; int pos = 0;
    if (l < L) {
        if (l < cnt) {
            int t = start + l;
            score = w.prob[t];
            tk = w.tok[t];
            pos = rel_idx[t] + boff[bq];
        }
        ss[l] = score; stk[l] = tk; sp[l] = pos;
    }
    __syncthreads();
    if (l < L) {
        int r = 0;
        for (int j = 0; j < L; ++j) {
            float x = ss[j];
            r += (x > score) || (x == score && j < l);
        }
        ss2[r] = score; stk2[r] = tk; sp2[r] = pos;
    }
    __syncthreads();

    int k = num_transfer[bq]; if (k < 0) k = 0;
    const float thrb = thresholds[bq];
    bool kp = false;
    if (l < L) {
        float s = ss2[l];
        kp = (l < k) && (s >= thrb) && (s > -INFINITY);
        out[bq * L + l] = kp ? sp2[l] : 0;
        out[bsz * L + bq * L + l] = kp ? stk2[l] : -1;
    }
    unsigned long long mask = __ballot(kp);
    if (l == 0) out[2 * bsz * L + bq] = (int)__popcll(mask);
}

extern "C" void kernel_launch(void* const* d_in, const int* in_sizes, int n_in,
                              void* d_out, int out_size, void* d_ws, size_t ws_size,
                              hipStream_t stream) {
    const float* logits   = (const float*)d_in[0];
    const int*   rel      = (const int*)d_in[1];
    const int*   boff     = (const int*)d_in[2];
    const int*   cuf      = (const int*)d_in[3];
    const int*   cuq      = (const int*)d_in[4];
    const float* temps    = (const float*)d_in[5];
    const int*   ntr      = (const int*)d_in[6];
    const float* thr      = (const float*)d_in[7];
    const float* topp     = (const float*)d_in[8];
    const int*   topk     = (const int*)d_in[9];

    const int total = in_sizes[1];
    const int bsz   = in_sizes[6];
    const long long logits_n = (long long)in_sizes[0];
    const int L = (out_size - bsz) / (2 * bsz);   // block_size

    zero_kernel<<<64, 256, 0, stream>>>(cuq, bsz, total, d_ws);

    mark_kernel<<<(total + 255) / 256, 256, 0, stream>>>(
        rel, cuf, cuq, bsz, total, d_ws);

    row_kernel<<<total, THREADS, 0, stream>>>(
        logits, cuq, topk, bsz, total, logits_n, d_ws);

    token_kernel<<<total, 64, 0, stream>>>(
        logits, rel, cuf, cuq, temps, topk, topp, bsz, total, logits_n, d_ws);

    finalize_kernel<<<bsz, 64, 0, stream>>>(
        rel, boff, cuf, cuq, ntr, thr, bsz, total, L, d_ws, (int*)d_out);
}

// Round 12
// 77.090 us; speedup vs baseline: 1.8626x; 1.4153x over previous
//
#include <hip/hip_runtime.h>
#include <math.h>

#define THREADS 256
#define CAP 512
#define HIST_BINS 2048
#define RAW_THRESH 2.5f
#define CHUNK 2048   // floats per staged chunk (8 KB)

__device__ __forceinline__ unsigned orderKey(float f) {
    unsigned u = __float_as_uint(f);
    return (u & 0x80000000u) ? ~u : (u | 0x80000000u);
}

// global->LDS DMA, 16B per lane. l is the WAVE-UNIFORM base; HW adds lane*16.
__device__ __forceinline__ void load_lds16(const float* g, float* l) {
    __builtin_amdgcn_global_load_lds(
        (const __attribute__((address_space(1))) void*)g,
        (__attribute__((address_space(3))) void*)l, 16, 0, 0);
}

// One block per candidate token (grid fully resident at 8 blocks/CU).
// Row streamed via chunked global_load_lds staging; collect scaled hits
// >= RAW_THRESH/T ... (raw >= RAW_THRESH, store x/T) into LDS; exact
// raw-space histogram fallback; LDS rank-sort; exact sequential epilogue.
__global__ __launch_bounds__(THREADS, 8) void token_kernel(
    const float* __restrict__ logits,
    const int* __restrict__ rel_idx,
    const int* __restrict__ cuf,
    const int* __restrict__ cuq,
    const float* __restrict__ temps,
    const int* __restrict__ topk_p,
    const float* __restrict__ topp_p,
    int bsz, int total, long long logits_n,
    float* __restrict__ prob, int* __restrict__ tok)
{
    __shared__ float buf[CHUNK];  // 8 KB staging
    __shared__ union {
        struct { float v[CAP]; int id[CAP]; float sv[CAP]; int si[CAP]; } a;  // 8 KB
        int hist[HIST_BINS];                                                  // 8 KB
    } u;
    __shared__ int s_n, s_m, s_amax;
    __shared__ unsigned s_T, s_maxkey;

    const int t = blockIdx.x;
    const int tid = threadIdx.x;
    const int wave = tid >> 6;
    const int lane = tid & 63;

    int lo = 0, hi = bsz;
    while (hi - lo > 1) { int mid = (lo + hi) >> 1; if (t >= cuf[mid]) lo = mid; else hi = mid; }
    const int nrows = cuq[bsz];
    const int vocab = (int)(logits_n / (long long)nrows);
    int kk = topk_p[0];
    if (kk > vocab) kk = vocab;
    const float T = temps[t];
    const float* rp = logits + ((long long)cuq[lo] + (long long)rel_idx[t]) * (long long)vocab;

    if (tid == 0) s_n = 0;

    // ---- chunked DMA stream: stage 8 KB to LDS, scan from LDS ----
    for (int c0 = 0; c0 < vocab; c0 += CHUNK) {
        const int cs = (CHUNK < vocab - c0) ? CHUNK : (vocab - c0);
        const int nfull = cs >> 8;              // 1KB call units (256 floats)
        for (int k = wave; k < nfull; k += 4)   // fire-and-forget DMA
            load_lds16(rp + c0 + (k << 8) + (lane << 2), buf + (k << 8));
        for (int j = (nfull << 8) + tid; j < cs; j += THREADS)  // remainder (none here)
            buf[j] = rp[c0 + j];
        __syncthreads();   // compiler drains vmcnt -> staged data visible

        for (int j4 = tid << 2; j4 < cs; j4 += THREADS << 2) {
            float a0 = buf[j4], a1 = buf[j4 + 1], a2 = buf[j4 + 2], a3 = buf[j4 + 3];
            float mx = fmaxf(fmaxf(a0, a1), fmaxf(a2, a3));
            if (mx >= RAW_THRESH) {
                if (a0 >= RAW_THRESH) { int p = atomicAdd(&s_n, 1); if (p < CAP) { u.a.v[p] = a0 / T; u.a.id[p] = c0 + j4; } }
                if (a1 >= RAW_THRESH) { int p = atomicAdd(&s_n, 1); if (p < CAP) { u.a.v[p] = a1 / T; u.a.id[p] = c0 + j4 + 1; } }
                if (a2 >= RAW_THRESH) { int p = atomicAdd(&s_n, 1); if (p < CAP) { u.a.v[p] = a2 / T; u.a.id[p] = c0 + j4 + 2; } }
                if (a3 >= RAW_THRESH) { int p = atomicAdd(&s_n, 1); if (p < CAP) { u.a.v[p] = a3 / T; u.a.id[p] = c0 + j4 + 3; } }
            }
        }
        __syncthreads();   // scan done before next chunk overwrites buf
    }
    int n = s_n;

    if (n < kk || n > CAP) {
        // ---- fallback: exact histogram threshold on scaled values ----
        __syncthreads();
        for (int j = tid; j < HIST_BINS; j += THREADS) u.hist[j] = 0;
        if (tid == 0) { s_n = 0; s_maxkey = 0; }
        __syncthreads();
        for (int j = tid; j < vocab; j += THREADS) {
            unsigned k = orderKey(rp[j] / T);
            atomicAdd(&u.hist[k >> 21], 1);
            atomicMax(&s_maxkey, k);
        }
        __syncthreads();
        if (tid == 0) {
            int B = (int)(s_maxkey >> 21);
            int cum = 0;
            while (true) {
                cum += u.hist[B];
                if (cum >= kk || B == 0) break;
                --B;
            }
            s_T = ((unsigned)B) << 21;
        }
        __syncthreads();
        const unsigned Tk = s_T;
        __syncthreads();   // hist reads done before union reuse
        for (int j = tid; j < vocab; j += THREADS) {
            float a = rp[j] / T;
            if (orderKey(a) >= Tk) {
                int p = atomicAdd(&s_n, 1);
                if (p < CAP) { u.a.v[p] = a; u.a.id[p] = j; }
            }
        }
        __syncthreads();
        n = s_n;
        if (n > CAP) n = CAP;
        if (kk > n) kk = n;
    }

    // ---- rank-sort collected scaled values (desc, original index asc) ----
    for (int j = tid; j < n; j += THREADS) {
        float v = u.a.v[j];
        int id = u.a.id[j];
        int rk = 0;
        for (int q = 0; q < n; ++q) {
            float x = u.a.v[q];
            rk += (x > v) || (x == v && u.a.id[q] < id);
        }
        u.a.sv[rk] = v;
        if (rk == 0) s_amax = id;   // first-index argmax
    }
    __syncthreads();

    if (tid == 0) {
        float thr = u.a.sv[kk - 1];
        int m = kk;
        while (m < n && u.a.sv[m] >= thr) ++m;  // ties at thr_k survive
        s_m = m;
    }
    __syncthreads();
    const int m = s_m;
    const float M = u.a.sv[0];
    for (int j = tid; j < m; j += THREADS) u.a.v[j] = expf(u.a.sv[j] - M);
    __syncthreads();
    if (tid == 0) {
        float Z1 = 0.f;
        for (int j = 0; j < m; ++j) Z1 += u.a.v[j];
        const float topp = topp_p[0];
        int jcut = m - 1;
        float c = 0.f;
        for (int j = 0; j < m; ++j) {
            float p = u.a.v[j] / Z1;
            c += p;
            if (c > topp) { jcut = j; break; }
        }
        float Z2 = 0.f;
        for (int j = 0; j <= jcut; ++j) Z2 += u.a.v[j];
        prob[t] = 1.0f / Z2;
        tok[t] = s_amax;
    }
}

// One wave per batch: stable sort by score desc, filter, write int32 outputs.
__global__ __launch_bounds__(64) void finalize_kernel(
    const float* __restrict__ prob,
    const int* __restrict__ tok,
    const int* __restrict__ rel_idx,
    const int* __restrict__ boff,
    const int* __restrict__ cuf,
    const int* __restrict__ num_transfer,
    const float* __restrict__ thresholds,
    int bsz, int L,
    int* __restrict__ out)
{
    const int bq = blockIdx.x;
    const int l = threadIdx.x;
    const int start = cuf[bq];
    int cnt = cuf[bq + 1] - start;
    if (cnt > L) cnt = L;

    __shared__ float ss[64]; __shared__ int stk[64]; __shared__ int sp[64];
    __shared__ float ss2[64]; __shared__ int stk2[64]; __shared__ int sp2[64];

    float score = -INFINITY; int tk = 0; int pos = 0;
    if (l < L) {
        if (l < cnt) {
            int t = start + l;
            score = prob[t];
            tk = tok[t];
            pos = rel_idx[t] + boff[bq];
        }
        ss[l] = score; stk[l] = tk; sp[l] = pos;
    }
    __syncthreads();
    if (l < L) {
        int r = 0;
        for (int j = 0; j < L; ++j) {
            float x = ss[j];
            r += (x > score) || (x == score && j < l);
        }
        ss2[r] = score; stk2[r] = tk; sp2[r] = pos;
    }
    __syncthreads();

    int k = num_transfer[bq]; if (k < 0) k = 0;
    const float thrb = thresholds[bq];
    bool kp = false;
    if (l < L) {
        float s = ss2[l];
        kp = (l < k) && (s >= thrb) && (s > -INFINITY);
        out[bq * L + l] = kp ? sp2[l] : 0;
        out[bsz * L + bq * L + l] = kp ? stk2[l] : -1;
    }
    unsigned long long mask = __ballot(kp);
    if (l == 0) out[2 * bsz * L + bq] = (int)__popcll(mask);
}

extern "C" void kernel_launch(void* const* d_in, const int* in_sizes, int n_in,
                              void* d_out, int out_size, void* d_ws, size_t ws_size,
                              hipStream_t stream) {
    const float* logits   = (const float*)d_in[0];
    const int*   rel      = (const int*)d_in[1];
    const int*   boff     = (const int*)d_in[2];
    const int*   cuf      = (const int*)d_in[3];
    const int*   cuq      = (const int*)d_in[4];
    const float* temps    = (const float*)d_in[5];
    const int*   ntr      = (const int*)d_in[6];
    const float* thr      = (const float*)d_in[7];
    const float* topp     = (const float*)d_in[8];
    const int*   topk     = (const int*)d_in[9];

    const int total = in_sizes[1];
    const int bsz   = in_sizes[6];
    const long long logits_n = (long long)in_sizes[0];
    const int L = (out_size - bsz) / (2 * bsz);   // block_size

    float* prob = (float*)d_ws;
    int*   tok  = (int*)(prob + total);

    token_kernel<<<total, THREADS, 0, stream>>>(
        logits, rel, cuf, cuq, temps, topk, topp, bsz, total, logits_n, prob, tok);

    finalize_kernel<<<bsz, 64, 0, stream>>>(
        prob, tok, rel, boff, cuf, ntr, thr, bsz, L, (int*)d_out);
}